// Round 20
// baseline (154.162 us; speedup 1.0000x reference)
//
#include <hip/hip_runtime.h>
#include <hip/hip_fp16.h>

#define N_NODES   50000
#define N_EDGES   800000
#define IN_FEAT   128
#define N_CLASSES 64
#define LDS_PADH  68    // 64 + 4 floats: row stride mod 32 banks = 4 -> 2-way (free)

// ---------------------------------------------------------------------------
// zero -> fused {count_rank | gemm} (parity blocks; gemm k-split 34KB LDS)
// -> scan (single kernel: per-block direct prefix base) -> scatter -> hops.
// adj uint16, rank uint16, tables fp16; per-edge dinv gathered in hop1.
// ---------------------------------------------------------------------------
__global__ void zero_cnt_kernel(int* __restrict__ cnt, int n) {
    int i = blockIdx.x * blockDim.x + threadIdx.x;
    if (i < n) cnt[i] = 0;
}

// Fused: even blocks count+rank (4 edges/thread, int4, the only atomic pass);
// odd blocks tiled y = x @ W^T, k split into two 64-halves staged into 34KB
// LDS (R18 proved direct-global loads are NOT a substitute: 50 -> 135 us).
__global__ __launch_bounds__(256) void count_gemm_kernel(
        const int* __restrict__ col, int* __restrict__ cnt,
        unsigned short* __restrict__ rank,
        const float* __restrict__ x, const float* __restrict__ W,
        __half* __restrict__ y, int e, int n) {
    __shared__ float xs[64][LDS_PADH];
    __shared__ float ws[64][LDS_PADH];
    int idx = (int)blockIdx.x >> 1;

    if ((blockIdx.x & 1) == 0) {
        // ---- count + rank ----
        int i = (idx * 256 + threadIdx.x) * 4;
        if (i + 3 < e) {
            int4 c = *(const int4*)(col + i);
            unsigned short r0 = (unsigned short)atomicAdd(&cnt[c.x], 1);
            unsigned short r1 = (unsigned short)atomicAdd(&cnt[c.y], 1);
            unsigned short r2 = (unsigned short)atomicAdd(&cnt[c.z], 1);
            unsigned short r3 = (unsigned short)atomicAdd(&cnt[c.w], 1);
            *(ushort4*)(rank + i) = make_ushort4(r0, r1, r2, r3);
        } else {
            for (int k = i; k < e; ++k)
                rank[k] = (unsigned short)atomicAdd(&cnt[col[k]], 1);
        }
        return;
    }

    // ---- gemm: y = x @ W^T (fp16 out), k split into halves of 64 ----
    int t = threadIdx.x;
    int rowbase = idx * 64;
    int rg = t >> 4;
    int cg = t & 15;
    float acc[4][4] = {};

    for (int half = 0; half < 2; ++half) {
        int kbase = half * 64;
        for (int i = t; i < 64 * 16; i += 256) {
            int r  = i >> 4;
            int kk = i & 15;
            *(float4*)(&ws[r][kk * 4]) =
                *(const float4*)(W + (size_t)r * IN_FEAT + kbase + kk * 4);
            int gr = rowbase + r;
            float4 v = make_float4(0.f, 0.f, 0.f, 0.f);
            if (gr < n) v = *(const float4*)(x + (size_t)gr * IN_FEAT + kbase + kk * 4);
            *(float4*)(&xs[r][kk * 4]) = v;
        }
        __syncthreads();

        for (int kk = 0; kk < 16; ++kk) {
            float4 a[4], bb[4];
#pragma unroll
            for (int i2 = 0; i2 < 4; ++i2) a[i2]  = *(float4*)(&xs[rg + 16 * i2][kk * 4]);
#pragma unroll
            for (int j = 0; j < 4; ++j) bb[j] = *(float4*)(&ws[cg + 16 * j][kk * 4]);
#pragma unroll
            for (int i2 = 0; i2 < 4; ++i2)
#pragma unroll
                for (int j = 0; j < 4; ++j)
                    acc[i2][j] += a[i2].x * bb[j].x + a[i2].y * bb[j].y +
                                  a[i2].z * bb[j].z + a[i2].w * bb[j].w;
        }
        __syncthreads();
    }

#pragma unroll
    for (int i2 = 0; i2 < 4; ++i2) {
        int gr = rowbase + rg + 16 * i2;
        if (gr < n) {
#pragma unroll
            for (int j = 0; j < 4; ++j)
                y[(size_t)gr * N_CLASSES + cg + 16 * j] = __float2half(acc[i2][j]);
        }
    }
}

// Single scan kernel: block b computes boff = sum(cnt[0..b*256)) directly
// (strided coalesced reads, cnt is 200KB L2-resident), then the per-chunk
// exclusive prefix + dinv.  Replaces the block_sum/apply_scan pair.
__global__ __launch_bounds__(256) void scan_kernel(const int* __restrict__ cnt,
                                                   int* __restrict__ rowptr,
                                                   float* __restrict__ dinv, int n) {
    __shared__ int s[256];
    int b = blockIdx.x, t = threadIdx.x;
    int limit = b * 256;

    // prefix base for this block
    int partial = 0;
    for (int i = t; i < limit; i += 256) partial += cnt[i];
    s[t] = partial;
    __syncthreads();
    for (int off = 128; off > 0; off >>= 1) {
        if (t < off) s[t] += s[t + off];
        __syncthreads();
    }
    int boff = s[0];
    __syncthreads();  // everyone has read s[0] before s is reused

    // local chunk scan
    int i = limit + t;
    int v = (i < n) ? cnt[i] : 0;
    s[t] = v;
    __syncthreads();
    for (int off = 1; off < 256; off <<= 1) {
        int add = (t >= off) ? s[t - off] : 0;
        __syncthreads();
        s[t] += add;
        __syncthreads();
    }
    if (i < n) {
        rowptr[i] = boff + s[t] - v;                 // exclusive prefix
        dinv[i]   = rsqrtf((float)(v + 1));          // +1 self loop
    }
    if (i == n - 1) rowptr[n] = boff + s[t];
}

__global__ void scatter_kernel(const int* __restrict__ row, const int* __restrict__ col,
                               const unsigned short* __restrict__ rank,
                               const int* __restrict__ rowptr,
                               unsigned short* __restrict__ adj, int e) {
    int i = (blockIdx.x * blockDim.x + threadIdx.x) * 4;
    if (i + 3 < e) {
        int4    r  = *(const int4*)(row + i);
        int4    c  = *(const int4*)(col + i);
        ushort4 rk = *(const ushort4*)(rank + i);
        adj[rowptr[c.x] + rk.x] = (unsigned short)r.x;
        adj[rowptr[c.y] + rk.y] = (unsigned short)r.y;
        adj[rowptr[c.z] + rk.z] = (unsigned short)r.z;
        adj[rowptr[c.w] + rk.w] = (unsigned short)r.w;
    } else {
        for (int k = i; k < e; ++k)
            adj[rowptr[col[k]] + rank[k]] = (unsigned short)row[k];
    }
}

// ---------------------------------------------------------------------------
// Hops on fp16 tables, fp32 accumulate; adj uint16.
// mode 0: w1[c] = fp16( dinv[c]^2 * ( dinv[c]*y[c] + sum_r dinv[r]*y[r] ) )
// mode 1: out[c] = fp32( dinv[c] * ( w1[c] + sum_r w1[r] ) + bias )
// ---------------------------------------------------------------------------
__global__ __launch_bounds__(256) void hop_sum_kernel(const int* __restrict__ rowptr,
                                                      const unsigned short* __restrict__ adj,
                                                      const float* __restrict__ dinv,
                                                      const __half* __restrict__ yin,
                                                      __half* __restrict__ yout_h,
                                                      float* __restrict__ yout_f,
                                                      const float* __restrict__ bias,
                                                      int mode, int n) {
    int sub  = threadIdx.x >> 6;
    int lane = threadIdx.x & 63;
    int node = blockIdx.x * 4 + sub;
    if (node >= n) return;

    int s  = rowptr[node];
    int e2 = rowptr[node + 1];
    float d = dinv[node];

    float acc;
    int k = s;
    if (mode == 0) {
        acc = d * __half2float(yin[(size_t)node * N_CLASSES + lane]);  // self
        for (; k + 7 < e2; k += 8) {
            int r0 = adj[k + 0], r1 = adj[k + 1], r2 = adj[k + 2], r3 = adj[k + 3];
            int r4 = adj[k + 4], r5 = adj[k + 5], r6 = adj[k + 6], r7 = adj[k + 7];
            float a0 = dinv[r0] * __half2float(yin[(size_t)r0 * N_CLASSES + lane]);
            float a1 = dinv[r1] * __half2float(yin[(size_t)r1 * N_CLASSES + lane]);
            float a2 = dinv[r2] * __half2float(yin[(size_t)r2 * N_CLASSES + lane]);
            float a3 = dinv[r3] * __half2float(yin[(size_t)r3 * N_CLASSES + lane]);
            float a4 = dinv[r4] * __half2float(yin[(size_t)r4 * N_CLASSES + lane]);
            float a5 = dinv[r5] * __half2float(yin[(size_t)r5 * N_CLASSES + lane]);
            float a6 = dinv[r6] * __half2float(yin[(size_t)r6 * N_CLASSES + lane]);
            float a7 = dinv[r7] * __half2float(yin[(size_t)r7 * N_CLASSES + lane]);
            acc += ((a0 + a1) + (a2 + a3)) + ((a4 + a5) + (a6 + a7));
        }
        for (; k < e2; ++k) {
            int r = adj[k];
            acc += dinv[r] * __half2float(yin[(size_t)r * N_CLASSES + lane]);
        }
        yout_h[(size_t)node * N_CLASSES + lane] = __float2half(d * d * acc);
    } else {
        acc = __half2float(yin[(size_t)node * N_CLASSES + lane]);  // self
        for (; k + 7 < e2; k += 8) {
            float v0 = __half2float(yin[(size_t)adj[k + 0] * N_CLASSES + lane]);
            float v1 = __half2float(yin[(size_t)adj[k + 1] * N_CLASSES + lane]);
            float v2 = __half2float(yin[(size_t)adj[k + 2] * N_CLASSES + lane]);
            float v3 = __half2float(yin[(size_t)adj[k + 3] * N_CLASSES + lane]);
            float v4 = __half2float(yin[(size_t)adj[k + 4] * N_CLASSES + lane]);
            float v5 = __half2float(yin[(size_t)adj[k + 5] * N_CLASSES + lane]);
            float v6 = __half2float(yin[(size_t)adj[k + 6] * N_CLASSES + lane]);
            float v7 = __half2float(yin[(size_t)adj[k + 7] * N_CLASSES + lane]);
            acc += ((v0 + v1) + (v2 + v3)) + ((v4 + v5) + (v6 + v7));
        }
        for (; k < e2; ++k)
            acc += __half2float(yin[(size_t)adj[k] * N_CLASSES + lane]);
        yout_f[(size_t)node * N_CLASSES + lane] = d * acc + bias[lane];
    }
}

// ---------------------------------------------------------------------------
extern "C" void kernel_launch(void* const* d_in, const int* in_sizes, int n_in,
                              void* d_out, int out_size, void* d_ws, size_t ws_size,
                              hipStream_t stream) {
    const float* x     = (const float*)d_in[0];
    const int*   edges = (const int*)d_in[1];   // int64 ref -> int32 device, [2, E] flat
    const float* W     = (const float*)d_in[2]; // [64, 128]
    const float* b     = (const float*)d_in[3]; // [64]
    float*       out   = (float*)d_out;         // [N, 64]

    const int* row = edges;            // sources
    const int* col = edges + N_EDGES;  // targets

    // Workspace map — ALL RANGES DISJOINT (verified).
    //   cnt    [      0 ..  200,000)
    //   rowptr [262,144 ..  462,148)
    //   dinv   [524,288 ..  724,288)
    //   adj    [1,048,576 .. 2,648,576)   uint16
    //   rank   [4,718,592 .. 6,318,592)   uint16
    //   y      [8,388,608 .. 14,788,608)  fp16
    //   w1     [16,777,216 .. 23,177,216) fp16
    char* ws = (char*)d_ws;
    int*            cnt    = (int*)(ws + 0);
    int*            rowptr = (int*)(ws + 256 * 1024);
    float*          dinv   = (float*)(ws + 512 * 1024);
    unsigned short* adj    = (unsigned short*)(ws + 1024 * 1024);
    unsigned short* rank   = (unsigned short*)(ws + 4608 * 1024);
    __half*         y      = (__half*)(ws + 8 * 1024 * 1024);
    __half*         w1     = (__half*)(ws + 16 * 1024 * 1024);

    const int nblk  = (N_NODES + 255) / 256;       // 196
    const int eblk4 = (N_EDGES / 4 + 255) / 256;   // 782
    const int gblk  = (N_NODES + 63) / 64;         // 782

    // CSR build + dinv; gemm overlapped with the atomic histogram.
    zero_cnt_kernel<<<nblk, 256, 0, stream>>>(cnt, N_NODES);
    count_gemm_kernel<<<eblk4 + gblk, 256, 0, stream>>>(col, cnt, rank, x, W, y,
                                                        N_EDGES, N_NODES);
    scan_kernel<<<nblk, 256, 0, stream>>>(cnt, rowptr, dinv, N_NODES);
    scatter_kernel<<<eblk4, 256, 0, stream>>>(row, col, rank, rowptr, adj, N_EDGES);

    // hop1: w1 = D^{-1}(A+I)D^{-1/2} y ;  hop2: out = D^{-1/2}(A+I) w1 + b
    hop_sum_kernel<<<(N_NODES + 3) / 4, 256, 0, stream>>>(rowptr, adj, dinv,
        y, w1, nullptr, nullptr, 0, N_NODES);
    hop_sum_kernel<<<(N_NODES + 3) / 4, 256, 0, stream>>>(rowptr, adj, dinv,
        w1, nullptr, out, b, 1, N_NODES);
}

// Round 21
// 132.844 us; speedup vs baseline: 1.1605x; 1.1605x over previous
//
#include <hip/hip_runtime.h>
#include <hip/hip_fp16.h>

#define N_NODES   50000
#define N_EDGES   800000
#define IN_FEAT   128
#define N_CLASSES 64
#define LDS_PADH  68    // 64 + 4 floats: row stride mod 32 banks = 4 -> 2-way (free)

// ---------------------------------------------------------------------------
// zero -> fused {count_rank | gemm} (parity blocks; gemm k-split -> 34KB LDS,
// 4 blocks/CU) -> block_sum -> apply_scan -> scatter -> hop1 -> hop2.
// adj uint16; tables fp16; per-edge dinv gathered in hop1 (free, R6).
// R20 lesson: do NOT merge the scan pair (redundant re-summing cost 21 us).
// ---------------------------------------------------------------------------
__global__ void zero_cnt_kernel(int* __restrict__ cnt, int n) {
    int i = blockIdx.x * blockDim.x + threadIdx.x;
    if (i < n) cnt[i] = 0;
}

// Fused: even blocks count+rank (4 edges/thread, int4); odd blocks do the
// tiled y = x @ W^T with the k-dim split in two 64-wide halves staged
// serially into half-size LDS (34KB total) -> 4 blocks/CU.
// (R18 proved direct-global broadcast reads are NOT a substitute: 50->135us.)
__global__ __launch_bounds__(256) void count_gemm_kernel(
        const int* __restrict__ col, int* __restrict__ cnt, int* __restrict__ rank,
        const float* __restrict__ x, const float* __restrict__ W,
        __half* __restrict__ y, int e, int n) {
    __shared__ float xs[64][LDS_PADH];
    __shared__ float ws[64][LDS_PADH];
    int idx = (int)blockIdx.x >> 1;

    if ((blockIdx.x & 1) == 0) {
        // ---- count + rank ----
        int i = (idx * 256 + threadIdx.x) * 4;
        if (i + 3 < e) {
            int4 c = *(const int4*)(col + i);
            int r0 = atomicAdd(&cnt[c.x], 1);
            int r1 = atomicAdd(&cnt[c.y], 1);
            int r2 = atomicAdd(&cnt[c.z], 1);
            int r3 = atomicAdd(&cnt[c.w], 1);
            *(int4*)(rank + i) = make_int4(r0, r1, r2, r3);
        } else {
            for (int k = i; k < e; ++k) rank[k] = atomicAdd(&cnt[col[k]], 1);
        }
        return;
    }

    // ---- gemm: y = x @ W^T (fp16 out), k split into halves of 64 ----
    int t = threadIdx.x;
    int rowbase = idx * 64;
    int rg = t >> 4;   // rows rg, rg+16, rg+32, rg+48
    int cg = t & 15;   // cols cg, cg+16, cg+32, cg+48
    float acc[4][4] = {};

    for (int half = 0; half < 2; ++half) {
        int kbase = half * 64;  // in floats
        for (int i = t; i < 64 * 16; i += 256) {
            int r  = i >> 4;
            int kk = i & 15;
            *(float4*)(&ws[r][kk * 4]) =
                *(const float4*)(W + (size_t)r * IN_FEAT + kbase + kk * 4);
            int gr = rowbase + r;
            float4 v = make_float4(0.f, 0.f, 0.f, 0.f);
            if (gr < n) v = *(const float4*)(x + (size_t)gr * IN_FEAT + kbase + kk * 4);
            *(float4*)(&xs[r][kk * 4]) = v;
        }
        __syncthreads();

        for (int kk = 0; kk < 16; ++kk) {
            float4 a[4], bb[4];
#pragma unroll
            for (int i2 = 0; i2 < 4; ++i2) a[i2]  = *(float4*)(&xs[rg + 16 * i2][kk * 4]);
#pragma unroll
            for (int j = 0; j < 4; ++j) bb[j] = *(float4*)(&ws[cg + 16 * j][kk * 4]);
#pragma unroll
            for (int i2 = 0; i2 < 4; ++i2)
#pragma unroll
                for (int j = 0; j < 4; ++j)
                    acc[i2][j] += a[i2].x * bb[j].x + a[i2].y * bb[j].y +
                                  a[i2].z * bb[j].z + a[i2].w * bb[j].w;
        }
        __syncthreads();  // before restaging (no-op cost on last half)
    }

#pragma unroll
    for (int i2 = 0; i2 < 4; ++i2) {
        int gr = rowbase + rg + 16 * i2;
        if (gr < n) {
#pragma unroll
            for (int j = 0; j < 4; ++j)
                y[(size_t)gr * N_CLASSES + cg + 16 * j] = __float2half(acc[i2][j]);
        }
    }
}

__global__ __launch_bounds__(256) void block_sum_kernel(const int* __restrict__ cnt,
                                                        int* __restrict__ bsum, int n) {
    __shared__ int s[256];
    int t = threadIdx.x;
    int i = blockIdx.x * 256 + t;
    s[t] = (i < n) ? cnt[i] : 0;
    __syncthreads();
    for (int off = 128; off > 0; off >>= 1) {
        if (t < off) s[t] += s[t + off];
        __syncthreads();
    }
    if (t == 0) bsum[blockIdx.x] = s[0];
}

// Each block: scan ALL 196 chunk sums in LDS, then per-element exclusive
// prefix for its own chunk + dinv.
__global__ __launch_bounds__(256) void apply_scan_kernel(const int* __restrict__ cnt,
                                                         const int* __restrict__ bsum,
                                                         int* __restrict__ rowptr,
                                                         float* __restrict__ dinv,
                                                         int n, int nch) {
    __shared__ int sb[256];
    __shared__ int s[256];
    int b = blockIdx.x, t = threadIdx.x;

    sb[t] = (t < nch) ? bsum[t] : 0;
    __syncthreads();
    for (int off = 1; off < 256; off <<= 1) {
        int add = (t >= off) ? sb[t - off] : 0;
        __syncthreads();
        sb[t] += add;
        __syncthreads();
    }

    int i = b * 256 + t;
    int v = (i < n) ? cnt[i] : 0;
    s[t] = v;
    __syncthreads();
    for (int off = 1; off < 256; off <<= 1) {
        int add = (t >= off) ? s[t - off] : 0;
        __syncthreads();
        s[t] += add;
        __syncthreads();
    }
    int boff = (b > 0) ? sb[b - 1] : 0;
    if (i < n) {
        rowptr[i] = boff + s[t] - v;                 // exclusive prefix
        dinv[i]   = rsqrtf((float)(v + 1));          // +1 self loop
    }
    if (i == n - 1) rowptr[n] = boff + s[t];
}

__global__ void scatter_kernel(const int* __restrict__ row, const int* __restrict__ col,
                               const int* __restrict__ rank, const int* __restrict__ rowptr,
                               unsigned short* __restrict__ adj, int e) {
    int i = (blockIdx.x * blockDim.x + threadIdx.x) * 4;
    if (i + 3 < e) {
        int4 r  = *(const int4*)(row + i);
        int4 c  = *(const int4*)(col + i);
        int4 rk = *(const int4*)(rank + i);
        adj[rowptr[c.x] + rk.x] = (unsigned short)r.x;
        adj[rowptr[c.y] + rk.y] = (unsigned short)r.y;
        adj[rowptr[c.z] + rk.z] = (unsigned short)r.z;
        adj[rowptr[c.w] + rk.w] = (unsigned short)r.w;
    } else {
        for (int k = i; k < e; ++k)
            adj[rowptr[col[k]] + rank[k]] = (unsigned short)row[k];
    }
}

// ---------------------------------------------------------------------------
// Hops on fp16 tables, fp32 accumulate; adj uint16.
// mode 0: w1[c] = fp16( dinv[c]^2 * ( dinv[c]*y[c] + sum_r dinv[r]*y[r] ) )
// mode 1: out[c] = fp32( dinv[c] * ( w1[c] + sum_r w1[r] ) + bias )
// ---------------------------------------------------------------------------
__global__ __launch_bounds__(256) void hop_sum_kernel(const int* __restrict__ rowptr,
                                                      const unsigned short* __restrict__ adj,
                                                      const float* __restrict__ dinv,
                                                      const __half* __restrict__ yin,
                                                      __half* __restrict__ yout_h,
                                                      float* __restrict__ yout_f,
                                                      const float* __restrict__ bias,
                                                      int mode, int n) {
    int sub  = threadIdx.x >> 6;
    int lane = threadIdx.x & 63;
    int node = blockIdx.x * 4 + sub;
    if (node >= n) return;

    int s  = rowptr[node];
    int e2 = rowptr[node + 1];
    float d = dinv[node];

    float acc;
    int k = s;
    if (mode == 0) {
        acc = d * __half2float(yin[(size_t)node * N_CLASSES + lane]);  // self
        for (; k + 7 < e2; k += 8) {
            int r0 = adj[k + 0], r1 = adj[k + 1], r2 = adj[k + 2], r3 = adj[k + 3];
            int r4 = adj[k + 4], r5 = adj[k + 5], r6 = adj[k + 6], r7 = adj[k + 7];
            float a0 = dinv[r0] * __half2float(yin[(size_t)r0 * N_CLASSES + lane]);
            float a1 = dinv[r1] * __half2float(yin[(size_t)r1 * N_CLASSES + lane]);
            float a2 = dinv[r2] * __half2float(yin[(size_t)r2 * N_CLASSES + lane]);
            float a3 = dinv[r3] * __half2float(yin[(size_t)r3 * N_CLASSES + lane]);
            float a4 = dinv[r4] * __half2float(yin[(size_t)r4 * N_CLASSES + lane]);
            float a5 = dinv[r5] * __half2float(yin[(size_t)r5 * N_CLASSES + lane]);
            float a6 = dinv[r6] * __half2float(yin[(size_t)r6 * N_CLASSES + lane]);
            float a7 = dinv[r7] * __half2float(yin[(size_t)r7 * N_CLASSES + lane]);
            acc += ((a0 + a1) + (a2 + a3)) + ((a4 + a5) + (a6 + a7));
        }
        for (; k < e2; ++k) {
            int r = adj[k];
            acc += dinv[r] * __half2float(yin[(size_t)r * N_CLASSES + lane]);
        }
        yout_h[(size_t)node * N_CLASSES + lane] = __float2half(d * d * acc);
    } else {
        acc = __half2float(yin[(size_t)node * N_CLASSES + lane]);  // self
        for (; k + 7 < e2; k += 8) {
            float v0 = __half2float(yin[(size_t)adj[k + 0] * N_CLASSES + lane]);
            float v1 = __half2float(yin[(size_t)adj[k + 1] * N_CLASSES + lane]);
            float v2 = __half2float(yin[(size_t)adj[k + 2] * N_CLASSES + lane]);
            float v3 = __half2float(yin[(size_t)adj[k + 3] * N_CLASSES + lane]);
            float v4 = __half2float(yin[(size_t)adj[k + 4] * N_CLASSES + lane]);
            float v5 = __half2float(yin[(size_t)adj[k + 5] * N_CLASSES + lane]);
            float v6 = __half2float(yin[(size_t)adj[k + 6] * N_CLASSES + lane]);
            float v7 = __half2float(yin[(size_t)adj[k + 7] * N_CLASSES + lane]);
            acc += ((v0 + v1) + (v2 + v3)) + ((v4 + v5) + (v6 + v7));
        }
        for (; k < e2; ++k)
            acc += __half2float(yin[(size_t)adj[k] * N_CLASSES + lane]);
        yout_f[(size_t)node * N_CLASSES + lane] = d * acc + bias[lane];
    }
}

// ---------------------------------------------------------------------------
extern "C" void kernel_launch(void* const* d_in, const int* in_sizes, int n_in,
                              void* d_out, int out_size, void* d_ws, size_t ws_size,
                              hipStream_t stream) {
    const float* x     = (const float*)d_in[0];
    const int*   edges = (const int*)d_in[1];   // int64 ref -> int32 device, [2, E] flat
    const float* W     = (const float*)d_in[2]; // [64, 128]
    const float* b     = (const float*)d_in[3]; // [64]
    float*       out   = (float*)d_out;         // [N, 64]

    const int* row = edges;            // sources
    const int* col = edges + N_EDGES;  // targets

    // Workspace map — ALL RANGES DISJOINT (verified).
    //   cnt    [      0 ..  200,000)
    //   rowptr [262,144 ..  462,148)
    //   dinv   [524,288 ..  724,288)
    //   bsum   [786,432 ..  787,216)
    //   adj    [1,048,576 .. 2,648,576)   uint16
    //   rank   [4,718,592 .. 7,918,592)
    //   y      [8,388,608 .. 14,788,608)  fp16
    //   w1     [16,777,216 .. 23,177,216) fp16
    char* ws = (char*)d_ws;
    int*            cnt    = (int*)(ws + 0);
    int*            rowptr = (int*)(ws + 256 * 1024);
    float*          dinv   = (float*)(ws + 512 * 1024);
    int*            bsum   = (int*)(ws + 768 * 1024);
    unsigned short* adj    = (unsigned short*)(ws + 1024 * 1024);
    int*            rank   = (int*)(ws + 4608 * 1024);
    __half*         y      = (__half*)(ws + 8 * 1024 * 1024);
    __half*         w1     = (__half*)(ws + 16 * 1024 * 1024);

    const int nblk  = (N_NODES + 255) / 256;       // 196
    const int eblk4 = (N_EDGES / 4 + 255) / 256;   // 782
    const int gblk  = (N_NODES + 63) / 64;         // 782

    // CSR build + dinv; gemm overlapped with the atomic histogram.
    zero_cnt_kernel<<<nblk, 256, 0, stream>>>(cnt, N_NODES);
    count_gemm_kernel<<<eblk4 + gblk, 256, 0, stream>>>(col, cnt, rank, x, W, y,
                                                        N_EDGES, N_NODES);
    block_sum_kernel<<<nblk, 256, 0, stream>>>(cnt, bsum, N_NODES);
    apply_scan_kernel<<<nblk, 256, 0, stream>>>(cnt, bsum, rowptr, dinv, N_NODES, nblk);
    scatter_kernel<<<eblk4, 256, 0, stream>>>(row, col, rank, rowptr, adj, N_EDGES);

    // hop1: w1 = D^{-1}(A+I)D^{-1/2} y ;  hop2: out = D^{-1/2}(A+I) w1 + b
    hop_sum_kernel<<<(N_NODES + 3) / 4, 256, 0, stream>>>(rowptr, adj, dinv,
        y, w1, nullptr, nullptr, 0, N_NODES);
    hop_sum_kernel<<<(N_NODES + 3) / 4, 256, 0, stream>>>(rowptr, adj, dinv,
        w1, nullptr, out, b, 1, N_NODES);
}